// Round 1
// baseline (736.348 us; speedup 1.0000x reference)
//
#include <hip/hip_runtime.h>

#define T_CTX 2048
#define C_DIM 1024
#define HQK   256
#define NVOC  50257

// ---------------------------------------------------------------------------
// Kernel 1: first-occurrence map + vocab->compact map
// first[s] = min s' with idx[s']==idx[s];  vocab_map[idx[f]] = f for firsts
// (vocab_map pre-set to -1 via memsetAsync 0xFF)
// ---------------------------------------------------------------------------
__global__ __launch_bounds__(256) void k_build_first(const int* __restrict__ idx,
                                                     int* __restrict__ first,
                                                     int* __restrict__ vocab_map) {
    __shared__ int sidx[T_CTX];
    for (int i = threadIdx.x; i < T_CTX; i += 256) sidx[i] = idx[i];
    __syncthreads();
    int s = blockIdx.x * 256 + threadIdx.x;
    if (s >= T_CTX) return;
    int my = sidx[s];
    int f = s;
    for (int s2 = 0; s2 < s; ++s2) {
        if (sidx[s2] == my) { f = s2; break; }
    }
    first[s] = f;
    if (f == s) vocab_map[my] = s;
}

// ---------------------------------------------------------------------------
// Kernel 2: fused q/k projection.  Output cols 0..255 -> qbuf [T][256] (row
// major), cols 256..511 -> kT [256][T] (TRANSPOSED so the score kernel reads
// k coalesced along s).
// fp32 tiled GEMM, 64x64 tile, 4x4 per thread, BK=16.
// ---------------------------------------------------------------------------
__global__ __launch_bounds__(256) void k_gemm_qk(const float* __restrict__ x,
                                                 const float* __restrict__ Wq,
                                                 const float* __restrict__ Wk,
                                                 float* __restrict__ qbuf,
                                                 float* __restrict__ kT) {
    __shared__ float As[16][65];   // [kk][row]
    __shared__ float Bs[16][65];   // [kk][col]
    const int bm = blockIdx.x;                 // 32 row tiles
    const int bn = blockIdx.y;                 // 8 col tiles (512 cols)
    const int row0 = bm * 64, col0 = bn * 64;
    const bool is_q = (col0 < HQK);
    const float* __restrict__ W = is_q ? Wq : Wk;
    const int wc0 = is_q ? col0 : (col0 - HQK);
    const int tid = threadIdx.x;
    const int tr = (tid >> 4) << 2;
    const int tc = (tid & 15) << 2;
    const int ar = tid >> 2, ak = (tid & 3) << 2;   // A load: row, k-offset
    const int bk = tid >> 4, bc = (tid & 15) << 2;  // B load: k, col-offset
    float acc[4][4] = {};
    for (int k0 = 0; k0 < C_DIM; k0 += 16) {
        float4 a4 = *reinterpret_cast<const float4*>(&x[(size_t)(row0 + ar) * C_DIM + k0 + ak]);
        float4 b4 = *reinterpret_cast<const float4*>(&W[(size_t)(k0 + bk) * HQK + wc0 + bc]);
        As[ak + 0][ar] = a4.x; As[ak + 1][ar] = a4.y; As[ak + 2][ar] = a4.z; As[ak + 3][ar] = a4.w;
        Bs[bk][bc + 0] = b4.x; Bs[bk][bc + 1] = b4.y; Bs[bk][bc + 2] = b4.z; Bs[bk][bc + 3] = b4.w;
        __syncthreads();
#pragma unroll
        for (int kk = 0; kk < 16; ++kk) {
            float av[4], bv[4];
#pragma unroll
            for (int i = 0; i < 4; ++i) av[i] = As[kk][tr + i];
#pragma unroll
            for (int j = 0; j < 4; ++j) bv[j] = Bs[kk][tc + j];
#pragma unroll
            for (int i = 0; i < 4; ++i)
#pragma unroll
                for (int j = 0; j < 4; ++j) acc[i][j] = fmaf(av[i], bv[j], acc[i][j]);
        }
        __syncthreads();
    }
    if (is_q) {
#pragma unroll
        for (int i = 0; i < 4; ++i)
#pragma unroll
            for (int j = 0; j < 4; ++j)
                qbuf[(size_t)(row0 + tr + i) * HQK + col0 + tc + j] = acc[i][j];
    } else {
#pragma unroll
        for (int i = 0; i < 4; ++i)
#pragma unroll
            for (int j = 0; j < 4; ++j)
                kT[(size_t)(wc0 + tc + j) * T_CTX + row0 + tr + i] = acc[i][j];
    }
}

// ---------------------------------------------------------------------------
// Kernel 3: causal scores + fold-by-first-occurrence.
// Block b owns 8 rows: {4b..4b+3} and {2044-4b..2047-4b} (triangular balance).
// Each thread owns 4 consecutive s; phase 1 reverses s assignment so the
// active thread ranges of the two phases are disjoint (intra-block balance).
// acc[8][2048] in LDS, accumulated via LDS atomics on first[s], then written
// to out_c (compact result) coalesced.
// ---------------------------------------------------------------------------
__global__ __launch_bounds__(512) void k_scores(const float* __restrict__ qbuf,
                                                const float* __restrict__ kT,
                                                const int* __restrict__ first,
                                                float* __restrict__ out_c) {
    __shared__ float qs[8][HQK];       // 8 KB
    __shared__ float acc[8][T_CTX];    // 64 KB
    __shared__ int   firsts[T_CTX];    // 8 KB
    const int b = blockIdx.x;          // 0..255
    const int tid = threadIdx.x;
    int trow[8];
#pragma unroll
    for (int j = 0; j < 4; ++j) trow[j] = 4 * b + j;
#pragma unroll
    for (int j = 0; j < 4; ++j) trow[4 + j] = 2044 - 4 * b + j;

    float* accf = &acc[0][0];
    for (int i = tid; i < 8 * T_CTX; i += 512) accf[i] = 0.0f;
    for (int i = tid; i < T_CTX; i += 512) firsts[i] = first[i];
    for (int i = tid; i < 8 * HQK; i += 512) {
        int r = i >> 8, d = i & 255;
        qs[r][d] = qbuf[(size_t)trow[r] * HQK + d];
    }
    __syncthreads();

    const float scale = 1.0f / 256.0f;
#pragma unroll
    for (int p = 0; p < 2; ++p) {
        const int jbase = p * 4;
        const int tmax = trow[jbase + 3];
        const int s0 = (p == 0) ? (tid << 2) : ((511 - tid) << 2);
        if (s0 <= tmax) {
            float dot[4][4] = {};   // [r][si]
            const float* kp = kT + s0;
#pragma unroll 2
            for (int d0 = 0; d0 < HQK; d0 += 4) {
                float4 kv0 = *reinterpret_cast<const float4*>(&kp[(size_t)(d0 + 0) * T_CTX]);
                float4 kv1 = *reinterpret_cast<const float4*>(&kp[(size_t)(d0 + 1) * T_CTX]);
                float4 kv2 = *reinterpret_cast<const float4*>(&kp[(size_t)(d0 + 2) * T_CTX]);
                float4 kv3 = *reinterpret_cast<const float4*>(&kp[(size_t)(d0 + 3) * T_CTX]);
#pragma unroll
                for (int r = 0; r < 4; ++r) {
                    float4 q4 = *reinterpret_cast<const float4*>(&qs[jbase + r][d0]);
                    dot[r][0] = fmaf(q4.x, kv0.x, fmaf(q4.y, kv1.x, fmaf(q4.z, kv2.x, fmaf(q4.w, kv3.x, dot[r][0]))));
                    dot[r][1] = fmaf(q4.x, kv0.y, fmaf(q4.y, kv1.y, fmaf(q4.z, kv2.y, fmaf(q4.w, kv3.y, dot[r][1]))));
                    dot[r][2] = fmaf(q4.x, kv0.z, fmaf(q4.y, kv1.z, fmaf(q4.z, kv2.z, fmaf(q4.w, kv3.z, dot[r][2]))));
                    dot[r][3] = fmaf(q4.x, kv0.w, fmaf(q4.y, kv1.w, fmaf(q4.z, kv2.w, fmaf(q4.w, kv3.w, dot[r][3]))));
                }
            }
#pragma unroll
            for (int si = 0; si < 4; ++si) {
                const int s = s0 + si;
                if (s > tmax) continue;
                const int f = firsts[s];
#pragma unroll
                for (int r = 0; r < 4; ++r) {
                    if (s <= trow[jbase + r]) atomicAdd(&acc[jbase + r][f], dot[r][si] * scale);
                }
            }
        }
    }
    __syncthreads();
    for (int i = tid; i < 8 * T_CTX; i += 512) {
        int j = i >> 11, f = i & 2047;
        out_c[(size_t)trow[j] * T_CTX + f] = acc[j][f];
    }
}

// ---------------------------------------------------------------------------
// Kernel 4: expand compact [T][2048] to full [T][VOCAB] in one streaming,
// coalesced write pass (this replaces any memset of d_out).
// out[t,v] = vocab_map[v] >= 0 ? out_c[t][vocab_map[v]] : 0
// float4 stores with per-row alignment fix ((t*50257) % 4 == t % 4).
// ---------------------------------------------------------------------------
__global__ __launch_bounds__(256) void k_expand(const float* __restrict__ out_c,
                                                const int* __restrict__ vocab_map,
                                                float* __restrict__ out) {
    __shared__ float rowc[T_CTX];
    const int t = blockIdx.x;
    for (int i = threadIdx.x; i < T_CTX; i += 256) rowc[i] = out_c[(size_t)t * T_CTX + i];
    __syncthreads();
    float* __restrict__ orow = out + (size_t)t * NVOC;
    const int lead = (4 - (t & 3)) & 3;
    if ((int)threadIdx.x < lead) {
        int m = vocab_map[threadIdx.x];
        orow[threadIdx.x] = (m >= 0) ? rowc[m] : 0.0f;
    }
    const int nvec = (NVOC - lead) >> 2;
    for (int i = threadIdx.x; i < nvec; i += 256) {
        const int v = lead + (i << 2);
        int m0 = vocab_map[v + 0], m1 = vocab_map[v + 1];
        int m2 = vocab_map[v + 2], m3 = vocab_map[v + 3];
        float4 o;
        o.x = (m0 >= 0) ? rowc[m0] : 0.0f;
        o.y = (m1 >= 0) ? rowc[m1] : 0.0f;
        o.z = (m2 >= 0) ? rowc[m2] : 0.0f;
        o.w = (m3 >= 0) ? rowc[m3] : 0.0f;
        *reinterpret_cast<float4*>(&orow[v]) = o;
    }
    for (int v = lead + (nvec << 2) + threadIdx.x; v < NVOC; v += 256) {
        int m = vocab_map[v];
        orow[v] = (m >= 0) ? rowc[m] : 0.0f;
    }
}

// ---------------------------------------------------------------------------
extern "C" void kernel_launch(void* const* d_in, const int* in_sizes, int n_in,
                              void* d_out, int out_size, void* d_ws, size_t ws_size,
                              hipStream_t stream) {
    const float* x  = (const float*)d_in[0];
    const int*   idx = (const int*)d_in[1];
    const float* Wq = (const float*)d_in[2];
    const float* Wk = (const float*)d_in[3];
    float* out = (float*)d_out;

    char* ws = (char*)d_ws;
    float* qbuf     = (float*)(ws);                              // 2 MB  [T][256]
    float* kT       = (float*)(ws + (2u << 20));                 // 2 MB  [256][T]
    float* out_c    = (float*)(ws + (4u << 20));                 // 16 MB [T][T]
    int*   first    = (int*)(ws + (20u << 20));                  // 8 KB
    int*   vocab_map = (int*)(ws + (20u << 20) + (16u << 10));   // ~200 KB

    hipMemsetAsync(vocab_map, 0xFF, NVOC * sizeof(int), stream);
    k_build_first<<<8, 256, 0, stream>>>(idx, first, vocab_map);
    dim3 gg(32, 8);
    k_gemm_qk<<<gg, 256, 0, stream>>>(x, Wq, Wk, qbuf, kT);
    k_scores<<<256, 512, 0, stream>>>(qbuf, kT, first, out_c);
    k_expand<<<T_CTX, 256, 0, stream>>>(out_c, vocab_map, out);
}

// Round 3
// 733.818 us; speedup vs baseline: 1.0034x; 1.0034x over previous
//
#include <hip/hip_runtime.h>

#define T_CTX 2048
#define C_DIM 1024
#define HQK   256
#define NVOC  50257

typedef float nfloat4 __attribute__((ext_vector_type(4)));

// ---------------------------------------------------------------------------
// Kernel 1: first-occurrence map + vocab->compact map
// first[s] = min s' with idx[s']==idx[s];  vocab_map[idx[f]] = f for firsts
// (vocab_map pre-set to -1 via memsetAsync 0xFF)
// ---------------------------------------------------------------------------
__global__ __launch_bounds__(256) void k_build_first(const int* __restrict__ idx,
                                                     int* __restrict__ first,
                                                     int* __restrict__ vocab_map) {
    __shared__ int sidx[T_CTX];
    for (int i = threadIdx.x; i < T_CTX; i += 256) sidx[i] = idx[i];
    __syncthreads();
    int s = blockIdx.x * 256 + threadIdx.x;
    if (s >= T_CTX) return;
    int my = sidx[s];
    int f = s;
    for (int s2 = 0; s2 < s; ++s2) {
        if (sidx[s2] == my) { f = s2; break; }
    }
    first[s] = f;
    if (f == s) vocab_map[my] = s;
}

// ---------------------------------------------------------------------------
// Kernel 2: fused q/k projection, 64x64 tile, BK=32, 4x4 micro via
// ds_read_b128 (LDS stride 68 floats = 272 B keeps rows 16B-aligned).
// cols 0..255 -> qbuf [T][256]; cols 256..511 -> kT [256][T] (transposed).
// ---------------------------------------------------------------------------
__global__ __launch_bounds__(256) void k_gemm_qk(const float* __restrict__ x,
                                                 const float* __restrict__ Wq,
                                                 const float* __restrict__ Wk,
                                                 float* __restrict__ qbuf,
                                                 float* __restrict__ kT) {
    __shared__ __align__(16) float As[32 * 68];   // [kk][row] transposed
    __shared__ __align__(16) float Bs[32 * 68];   // [kk][col]
    const int row0 = blockIdx.x * 64;
    const int col0 = blockIdx.y * 64;
    const bool is_q = (col0 < HQK);
    const float* __restrict__ W = is_q ? Wq : Wk;
    const int wc0 = is_q ? col0 : (col0 - HQK);
    const int tid = threadIdx.x;
    const int tr = (tid >> 4) << 2;
    const int tc = (tid & 15) << 2;
    float acc[4][4] = {};
    for (int k0 = 0; k0 < C_DIM; k0 += 32) {
#pragma unroll
        for (int L = 0; L < 2; ++L) {
            const int id = tid + 256 * L;
            const int ar = id >> 3, ak = (id & 7) << 2;
            float4 a4 = *reinterpret_cast<const float4*>(&x[(size_t)(row0 + ar) * C_DIM + k0 + ak]);
            As[(ak + 0) * 68 + ar] = a4.x; As[(ak + 1) * 68 + ar] = a4.y;
            As[(ak + 2) * 68 + ar] = a4.z; As[(ak + 3) * 68 + ar] = a4.w;
            const int bk = id >> 4, bc = (id & 15) << 2;
            float4 b4 = *reinterpret_cast<const float4*>(&W[(size_t)(k0 + bk) * HQK + wc0 + bc]);
            *reinterpret_cast<float4*>(&Bs[bk * 68 + bc]) = b4;
        }
        __syncthreads();
#pragma unroll
        for (int kk = 0; kk < 32; ++kk) {
            float4 av = *reinterpret_cast<const float4*>(&As[kk * 68 + tr]);
            float4 bv = *reinterpret_cast<const float4*>(&Bs[kk * 68 + tc]);
            const float a[4] = {av.x, av.y, av.z, av.w};
            const float b[4] = {bv.x, bv.y, bv.z, bv.w};
#pragma unroll
            for (int i = 0; i < 4; ++i)
#pragma unroll
                for (int j = 0; j < 4; ++j) acc[i][j] = fmaf(a[i], b[j], acc[i][j]);
        }
        __syncthreads();
    }
    if (is_q) {
#pragma unroll
        for (int i = 0; i < 4; ++i) {
            float4 o = {acc[i][0], acc[i][1], acc[i][2], acc[i][3]};
            *reinterpret_cast<float4*>(&qbuf[(size_t)(row0 + tr + i) * HQK + col0 + tc]) = o;
        }
    } else {
#pragma unroll
        for (int j = 0; j < 4; ++j) {
            float4 o = {acc[0][j], acc[1][j], acc[2][j], acc[3][j]};
            *reinterpret_cast<float4*>(&kT[(size_t)(wc0 + tc + j) * T_CTX + row0 + tr]) = o;
        }
    }
}

// ---------------------------------------------------------------------------
// Kernel 3: causal score GEMM.  c[t][s] = q[t].k[s] / 256 for causal tiles
// (tile_s <= tile_t; diagonal tiles compute garbage above diagonal which the
// fold kernel masks).  Same 64x64/BK=32/b128 structure; K=256 -> 8 iters.
// Grid 32x32, upper-triangular blocks exit immediately.
// ---------------------------------------------------------------------------
__global__ __launch_bounds__(256) void k_scores_gemm(const float* __restrict__ q,
                                                     const float* __restrict__ kT,
                                                     float* __restrict__ c) {
    const int bt = blockIdx.x, bs = blockIdx.y;
    if (bs > bt) return;
    __shared__ __align__(16) float As[32 * 68];
    __shared__ __align__(16) float Bs[32 * 68];
    const int row0 = bt * 64;   // t
    const int col0 = bs * 64;   // s
    const int tid = threadIdx.x;
    const int tr = (tid >> 4) << 2;
    const int tc = (tid & 15) << 2;
    float acc[4][4] = {};
    for (int k0 = 0; k0 < HQK; k0 += 32) {
#pragma unroll
        for (int L = 0; L < 2; ++L) {
            const int id = tid + 256 * L;
            const int ar = id >> 3, ak = (id & 7) << 2;
            float4 a4 = *reinterpret_cast<const float4*>(&q[(size_t)(row0 + ar) * HQK + k0 + ak]);
            As[(ak + 0) * 68 + ar] = a4.x; As[(ak + 1) * 68 + ar] = a4.y;
            As[(ak + 2) * 68 + ar] = a4.z; As[(ak + 3) * 68 + ar] = a4.w;
            const int bk = id >> 4, bc = (id & 15) << 2;
            float4 b4 = *reinterpret_cast<const float4*>(&kT[(size_t)(k0 + bk) * T_CTX + col0 + bc]);
            *reinterpret_cast<float4*>(&Bs[bk * 68 + bc]) = b4;
        }
        __syncthreads();
#pragma unroll
        for (int kk = 0; kk < 32; ++kk) {
            float4 av = *reinterpret_cast<const float4*>(&As[kk * 68 + tr]);
            float4 bv = *reinterpret_cast<const float4*>(&Bs[kk * 68 + tc]);
            const float a[4] = {av.x, av.y, av.z, av.w};
            const float b[4] = {bv.x, bv.y, bv.z, bv.w};
#pragma unroll
            for (int i = 0; i < 4; ++i)
#pragma unroll
                for (int j = 0; j < 4; ++j) acc[i][j] = fmaf(a[i], b[j], acc[i][j]);
        }
        __syncthreads();
    }
    const float scale = 1.0f / 256.0f;
#pragma unroll
    for (int i = 0; i < 4; ++i) {
        float4 o = {acc[i][0] * scale, acc[i][1] * scale, acc[i][2] * scale, acc[i][3] * scale};
        *reinterpret_cast<float4*>(&c[(size_t)(row0 + tr + i) * T_CTX + col0 + tc]) = o;
    }
}

// ---------------------------------------------------------------------------
// Kernel 4: fold columns of c by first-occurrence into compact out_c [T][T].
// Block b owns rows {4b..4b+3, 2044-4b..2047-4b} (triangular balance).
// Each thread handles at most one float4 of each row (tid*4 <= t).
// ---------------------------------------------------------------------------
__global__ __launch_bounds__(512) void k_fold(const float* __restrict__ c,
                                              const int* __restrict__ first,
                                              float* __restrict__ out_c) {
    __shared__ float acc[8][T_CTX];    // 64 KB
    __shared__ int   firsts[T_CTX];    // 8 KB
    const int b = blockIdx.x;
    const int tid = threadIdx.x;
    int trow[8];
#pragma unroll
    for (int j = 0; j < 4; ++j) trow[j] = 4 * b + j;
#pragma unroll
    for (int j = 0; j < 4; ++j) trow[4 + j] = 2044 - 4 * b + j;
    float4* accf4 = reinterpret_cast<float4*>(&acc[0][0]);
    for (int i = tid; i < 8 * T_CTX / 4; i += 512) accf4[i] = make_float4(0.f, 0.f, 0.f, 0.f);
    for (int i = tid; i < T_CTX; i += 512) firsts[i] = first[i];
    __syncthreads();
#pragma unroll
    for (int r = 0; r < 8; ++r) {
        const int t = trow[r];
        const int s0 = tid << 2;
        if (s0 <= t) {
            float4 v = *reinterpret_cast<const float4*>(&c[(size_t)t * T_CTX + s0]);
            const float vv[4] = {v.x, v.y, v.z, v.w};
#pragma unroll
            for (int si = 0; si < 4; ++si) {
                if (s0 + si <= t) atomicAdd(&acc[r][firsts[s0 + si]], vv[si]);
            }
        }
    }
    __syncthreads();
    for (int i = tid; i < 8 * T_CTX / 4; i += 512) {
        const int j = i >> 9, f4 = (i & 511) << 2;
        *reinterpret_cast<float4*>(&out_c[(size_t)trow[j] * T_CTX + f4]) =
            *reinterpret_cast<const float4*>(&acc[j][f4]);
    }
}

// ---------------------------------------------------------------------------
// Kernel 5: expand compact [T][2048] to full [T][VOCAB], one streaming
// coalesced nontemporal-write pass.
// out[t,v] = vocab_map[v] >= 0 ? out_c[t][vocab_map[v]] : 0
// ---------------------------------------------------------------------------
__global__ __launch_bounds__(256) void k_expand(const float* __restrict__ out_c,
                                                const int* __restrict__ vocab_map,
                                                float* __restrict__ out) {
    __shared__ float rowc[T_CTX];
    const int t = blockIdx.x;
    for (int i = threadIdx.x; i < T_CTX; i += 256) rowc[i] = out_c[(size_t)t * T_CTX + i];
    __syncthreads();
    float* __restrict__ orow = out + (size_t)t * NVOC;
    const int lead = (4 - (t & 3)) & 3;
    if ((int)threadIdx.x < lead) {
        int m = vocab_map[threadIdx.x];
        orow[threadIdx.x] = (m >= 0) ? rowc[m] : 0.0f;
    }
    const int nvec = (NVOC - lead) >> 2;
    for (int i = threadIdx.x; i < nvec; i += 256) {
        const int v = lead + (i << 2);
        int m0 = vocab_map[v + 0], m1 = vocab_map[v + 1];
        int m2 = vocab_map[v + 2], m3 = vocab_map[v + 3];
        nfloat4 o;
        o.x = (m0 >= 0) ? rowc[m0] : 0.0f;
        o.y = (m1 >= 0) ? rowc[m1] : 0.0f;
        o.z = (m2 >= 0) ? rowc[m2] : 0.0f;
        o.w = (m3 >= 0) ? rowc[m3] : 0.0f;
        __builtin_nontemporal_store(o, reinterpret_cast<nfloat4*>(&orow[v]));
    }
    for (int v = lead + (nvec << 2) + threadIdx.x; v < NVOC; v += 256) {
        int m = vocab_map[v];
        orow[v] = (m >= 0) ? rowc[m] : 0.0f;
    }
}

// ---------------------------------------------------------------------------
extern "C" void kernel_launch(void* const* d_in, const int* in_sizes, int n_in,
                              void* d_out, int out_size, void* d_ws, size_t ws_size,
                              hipStream_t stream) {
    const float* x   = (const float*)d_in[0];
    const int*   idx = (const int*)d_in[1];
    const float* Wq  = (const float*)d_in[2];
    const float* Wk  = (const float*)d_in[3];
    float* out = (float*)d_out;

    char* ws = (char*)d_ws;
    float* qbuf      = (float*)(ws);                              // 2 MB  [T][256]
    float* kT        = (float*)(ws + (2u << 20));                 // 2 MB  [256][T]
    float* c         = (float*)(ws + (4u << 20));                 // 16 MB [T][T] raw scores
    float* out_c     = (float*)(ws + (20u << 20));                // 16 MB [T][T] folded
    int*   first     = (int*)(ws + (36u << 20));                  // 8 KB
    int*   vocab_map = (int*)(ws + (36u << 20) + (16u << 10));    // ~200 KB

    (void)hipMemsetAsync(vocab_map, 0xFF, NVOC * sizeof(int), stream);
    k_build_first<<<8, 256, 0, stream>>>(idx, first, vocab_map);
    dim3 gg(32, 8);
    k_gemm_qk<<<gg, 256, 0, stream>>>(x, Wq, Wk, qbuf, kT);
    dim3 gs(32, 32);
    k_scores_gemm<<<gs, 256, 0, stream>>>(qbuf, kT, c);
    k_fold<<<256, 512, 0, stream>>>(c, first, out_c);
    k_expand<<<T_CTX, 256, 0, stream>>>(out_c, vocab_map, out);
}

// Round 5
// 720.276 us; speedup vs baseline: 1.0223x; 1.0188x over previous
//
#include <hip/hip_runtime.h>

#define T_CTX 2048
#define C_DIM 1024
#define HQK   256
#define NVOC  50257

typedef float nfloat4 __attribute__((ext_vector_type(4)));

// ---------------------------------------------------------------------------
// Kernel 1: first-occurrence map + vocab->compact map
// first[s] = min s' with idx[s']==idx[s];  vocab_map[idx[f]] = f for firsts
// (vocab_map pre-set to -1 via memsetAsync 0xFF)
// ---------------------------------------------------------------------------
__global__ __launch_bounds__(256) void k_build_first(const int* __restrict__ idx,
                                                     int* __restrict__ first,
                                                     int* __restrict__ vocab_map) {
    __shared__ int sidx[T_CTX];
    for (int i = threadIdx.x; i < T_CTX; i += 256) sidx[i] = idx[i];
    __syncthreads();
    int s = blockIdx.x * 256 + threadIdx.x;
    if (s >= T_CTX) return;
    int my = sidx[s];
    int f = s;
    for (int s2 = 0; s2 < s; ++s2) {
        if (sidx[s2] == my) { f = s2; break; }
    }
    first[s] = f;
    if (f == s) vocab_map[my] = s;
}

// ---------------------------------------------------------------------------
// Kernel 2: fused q/k projection, 64x64 tile, BK=32, 4x4 micro via
// ds_read_b128 (LDS stride 68 floats = 272 B keeps rows 16B-aligned).
// cols 0..255 -> qbuf [T][256]; cols 256..511 -> kT [256][T] (transposed).
// ---------------------------------------------------------------------------
__global__ __launch_bounds__(256) void k_gemm_qk(const float* __restrict__ x,
                                                 const float* __restrict__ Wq,
                                                 const float* __restrict__ Wk,
                                                 float* __restrict__ qbuf,
                                                 float* __restrict__ kT) {
    __shared__ __align__(16) float As[32 * 68];   // [kk][row] transposed
    __shared__ __align__(16) float Bs[32 * 68];   // [kk][col]
    const int row0 = blockIdx.x * 64;
    const int col0 = blockIdx.y * 64;
    const bool is_q = (col0 < HQK);
    const float* __restrict__ W = is_q ? Wq : Wk;
    const int wc0 = is_q ? col0 : (col0 - HQK);
    const int tid = threadIdx.x;
    const int tr = (tid >> 4) << 2;
    const int tc = (tid & 15) << 2;
    float acc[4][4] = {};
    for (int k0 = 0; k0 < C_DIM; k0 += 32) {
#pragma unroll
        for (int L = 0; L < 2; ++L) {
            const int id = tid + 256 * L;
            const int ar = id >> 3, ak = (id & 7) << 2;
            float4 a4 = *reinterpret_cast<const float4*>(&x[(size_t)(row0 + ar) * C_DIM + k0 + ak]);
            As[(ak + 0) * 68 + ar] = a4.x; As[(ak + 1) * 68 + ar] = a4.y;
            As[(ak + 2) * 68 + ar] = a4.z; As[(ak + 3) * 68 + ar] = a4.w;
            const int bk = id >> 4, bc = (id & 15) << 2;
            float4 b4 = *reinterpret_cast<const float4*>(&W[(size_t)(k0 + bk) * HQK + wc0 + bc]);
            *reinterpret_cast<float4*>(&Bs[bk * 68 + bc]) = b4;
        }
        __syncthreads();
#pragma unroll
        for (int kk = 0; kk < 32; ++kk) {
            float4 av = *reinterpret_cast<const float4*>(&As[kk * 68 + tr]);
            float4 bv = *reinterpret_cast<const float4*>(&Bs[kk * 68 + tc]);
            const float a[4] = {av.x, av.y, av.z, av.w};
            const float b[4] = {bv.x, bv.y, bv.z, bv.w};
#pragma unroll
            for (int i = 0; i < 4; ++i)
#pragma unroll
                for (int j = 0; j < 4; ++j) acc[i][j] = fmaf(a[i], b[j], acc[i][j]);
        }
        __syncthreads();
    }
    if (is_q) {
#pragma unroll
        for (int i = 0; i < 4; ++i) {
            float4 o = {acc[i][0], acc[i][1], acc[i][2], acc[i][3]};
            *reinterpret_cast<float4*>(&qbuf[(size_t)(row0 + tr + i) * HQK + col0 + tc]) = o;
        }
    } else {
#pragma unroll
        for (int j = 0; j < 4; ++j) {
            float4 o = {acc[0][j], acc[1][j], acc[2][j], acc[3][j]};
            *reinterpret_cast<float4*>(&kT[(size_t)(wc0 + tc + j) * T_CTX + row0 + tr]) = o;
        }
    }
}

// ---------------------------------------------------------------------------
// Kernel 3: causal score GEMM.  c[t][s] = q[t].k[s] / 256 for causal tiles
// (tile_s <= tile_t; diagonal tiles compute garbage above diagonal which the
// fold masks).  64x64/BK=32/b128 structure; K=256 -> 8 iters.
// Grid 32x32, upper-triangular blocks exit immediately.
// ---------------------------------------------------------------------------
__global__ __launch_bounds__(256) void k_scores_gemm(const float* __restrict__ q,
                                                     const float* __restrict__ kT,
                                                     float* __restrict__ c) {
    const int bt = blockIdx.x, bs = blockIdx.y;
    if (bs > bt) return;
    __shared__ __align__(16) float As[32 * 68];
    __shared__ __align__(16) float Bs[32 * 68];
    const int row0 = bt * 64;   // t
    const int col0 = bs * 64;   // s
    const int tid = threadIdx.x;
    const int tr = (tid >> 4) << 2;
    const int tc = (tid & 15) << 2;
    float acc[4][4] = {};
    for (int k0 = 0; k0 < HQK; k0 += 32) {
#pragma unroll
        for (int L = 0; L < 2; ++L) {
            const int id = tid + 256 * L;
            const int ar = id >> 3, ak = (id & 7) << 2;
            float4 a4 = *reinterpret_cast<const float4*>(&q[(size_t)(row0 + ar) * HQK + k0 + ak]);
            As[(ak + 0) * 68 + ar] = a4.x; As[(ak + 1) * 68 + ar] = a4.y;
            As[(ak + 2) * 68 + ar] = a4.z; As[(ak + 3) * 68 + ar] = a4.w;
            const int bk = id >> 4, bc = (id & 15) << 2;
            float4 b4 = *reinterpret_cast<const float4*>(&kT[(size_t)(k0 + bk) * T_CTX + col0 + bc]);
            *reinterpret_cast<float4*>(&Bs[bk * 68 + bc]) = b4;
        }
        __syncthreads();
#pragma unroll
        for (int kk = 0; kk < 32; ++kk) {
            float4 av = *reinterpret_cast<const float4*>(&As[kk * 68 + tr]);
            float4 bv = *reinterpret_cast<const float4*>(&Bs[kk * 68 + tc]);
            const float a[4] = {av.x, av.y, av.z, av.w};
            const float b[4] = {bv.x, bv.y, bv.z, bv.w};
#pragma unroll
            for (int i = 0; i < 4; ++i)
#pragma unroll
                for (int j = 0; j < 4; ++j) acc[i][j] = fmaf(a[i], b[j], acc[i][j]);
        }
        __syncthreads();
    }
    const float scale = 1.0f / 256.0f;
#pragma unroll
    for (int i = 0; i < 4; ++i) {
        float4 o = {acc[i][0] * scale, acc[i][1] * scale, acc[i][2] * scale, acc[i][3] * scale};
        *reinterpret_cast<float4*>(&c[(size_t)(row0 + tr + i) * T_CTX + col0 + tc]) = o;
    }
}

// ---------------------------------------------------------------------------
// Kernel 4 (fused fold+expand): block t
//   phase A: fold row t of c by first[] into LDS rowc[2048] (LDS atomics,
//            <=2 iterations of float4+int4 loads per thread)
//   phase B: stream-expand rowc to out[t][0..VOCAB) with aligned nontemporal
//            float4 stores (per-row lead fixup since NVOC%4==1).
// out[t,v] = vocab_map[v] >= 0 ? rowc[vocab_map[v]] : 0
// ---------------------------------------------------------------------------
__global__ __launch_bounds__(256) void k_fold_expand(const float* __restrict__ c,
                                                     const int* __restrict__ first,
                                                     const int* __restrict__ vocab_map,
                                                     float* __restrict__ out) {
    __shared__ float rowc[T_CTX];
    const int t = blockIdx.x;
    for (int i = threadIdx.x; i < T_CTX; i += 256) rowc[i] = 0.0f;
    __syncthreads();
    // fold: s in [0, t]
    const int nq = (t >> 2) + 1;   // quads covering s=0..t
    for (int qd = threadIdx.x; qd < nq; qd += 256) {
        const int s0 = qd << 2;
        float4 v = *reinterpret_cast<const float4*>(&c[(size_t)t * T_CTX + s0]);
        int4 f4 = *reinterpret_cast<const int4*>(&first[s0]);
        if (s0 + 3 <= t) {
            atomicAdd(&rowc[f4.x], v.x); atomicAdd(&rowc[f4.y], v.y);
            atomicAdd(&rowc[f4.z], v.z); atomicAdd(&rowc[f4.w], v.w);
        } else {
            atomicAdd(&rowc[f4.x], v.x);
            if (s0 + 1 <= t) atomicAdd(&rowc[f4.y], v.y);
            if (s0 + 2 <= t) atomicAdd(&rowc[f4.z], v.z);
            if (s0 + 3 <= t) atomicAdd(&rowc[f4.w], v.w);
        }
    }
    __syncthreads();
    // expand
    float* __restrict__ orow = out + (size_t)t * NVOC;
    const int lead = (4 - (t & 3)) & 3;   // (t*NVOC + lead) % 4 == 0
    if ((int)threadIdx.x < lead) {
        int m = vocab_map[threadIdx.x];
        orow[threadIdx.x] = (m >= 0) ? rowc[m] : 0.0f;
    }
    const int nvec = (NVOC - lead) >> 2;
    for (int i = threadIdx.x; i < nvec; i += 256) {
        const int v = lead + (i << 2);
        int m0 = vocab_map[v + 0], m1 = vocab_map[v + 1];
        int m2 = vocab_map[v + 2], m3 = vocab_map[v + 3];
        nfloat4 o;
        o.x = (m0 >= 0) ? rowc[m0] : 0.0f;
        o.y = (m1 >= 0) ? rowc[m1] : 0.0f;
        o.z = (m2 >= 0) ? rowc[m2] : 0.0f;
        o.w = (m3 >= 0) ? rowc[m3] : 0.0f;
        __builtin_nontemporal_store(o, reinterpret_cast<nfloat4*>(&orow[v]));
    }
    for (int v = lead + (nvec << 2) + threadIdx.x; v < NVOC; v += 256) {
        int m = vocab_map[v];
        orow[v] = (m >= 0) ? rowc[m] : 0.0f;
    }
}

// ---------------------------------------------------------------------------
extern "C" void kernel_launch(void* const* d_in, const int* in_sizes, int n_in,
                              void* d_out, int out_size, void* d_ws, size_t ws_size,
                              hipStream_t stream) {
    const float* x   = (const float*)d_in[0];
    const int*   idx = (const int*)d_in[1];
    const float* Wq  = (const float*)d_in[2];
    const float* Wk  = (const float*)d_in[3];
    float* out = (float*)d_out;

    char* ws = (char*)d_ws;
    float* qbuf      = (float*)(ws);                              // 2 MB  [T][256]
    float* kT        = (float*)(ws + (2u << 20));                 // 2 MB  [256][T]
    float* c         = (float*)(ws + (4u << 20));                 // 16 MB [T][T] raw scores
    int*   first     = (int*)(ws + (20u << 20));                  // 8 KB
    int*   vocab_map = (int*)(ws + (20u << 20) + (16u << 10));    // ~200 KB

    (void)hipMemsetAsync(vocab_map, 0xFF, NVOC * sizeof(int), stream);
    k_build_first<<<8, 256, 0, stream>>>(idx, first, vocab_map);
    dim3 gg(32, 8);
    k_gemm_qk<<<gg, 256, 0, stream>>>(x, Wq, Wk, qbuf, kT);
    dim3 gs(32, 32);
    k_scores_gemm<<<gs, 256, 0, stream>>>(qbuf, kT, c);
    k_fold_expand<<<T_CTX, 256, 0, stream>>>(c, first, vocab_map, out);
}

// Round 6
// 564.546 us; speedup vs baseline: 1.3043x; 1.2758x over previous
//
#include <hip/hip_runtime.h>

#define T_CTX 2048
#define C_DIM 1024
#define HQK   256
#define NVOC  50257

typedef float nfloat4 __attribute__((ext_vector_type(4)));

// ---------------------------------------------------------------------------
// Kernel 1 (single block, 1024 thr): clears vocab_map AND builds
// first-occurrence map via an LDS hash table (atomicCAS claim + atomicMin pos).
// first[s] = min s' with idx[s']==idx[s];  vocab_map[idx[f]] = f for firsts;
// vocab_map[v] = -1 elsewhere.  Replaces memsetAsync + O(T^2) scan.
// ---------------------------------------------------------------------------
__global__ __launch_bounds__(1024) void k_build_first(const int* __restrict__ idx,
                                                      int* __restrict__ first,
                                                      int* __restrict__ vocab_map) {
    __shared__ int sidx[T_CTX];
    __shared__ int skey[4096];
    __shared__ int sval[4096];
    const int tid = threadIdx.x;
    for (int i = tid; i < T_CTX; i += 1024) sidx[i] = idx[i];
    for (int i = tid; i < 4096; i += 1024) { skey[i] = -1; sval[i] = 0x7fffffff; }
    // clear vocab_map to -1 (int4 stores; NVOC = 4*12564 + 1)
    int4* vm4 = reinterpret_cast<int4*>(vocab_map);
    const int4 neg1 = make_int4(-1, -1, -1, -1);
    for (int i = tid; i < 12564; i += 1024) vm4[i] = neg1;
    if (tid == 0) vocab_map[NVOC - 1] = -1;
    __syncthreads();
    // insert phase
#pragma unroll
    for (int rep = 0; rep < 2; ++rep) {
        const int s = tid + rep * 1024;
        const int my = sidx[s];
        int h = (int)(((unsigned)my * 2654435761u) >> 16) & 4095;
        while (true) {
            int k = skey[h];
            if (k == my) break;
            if (k == -1) {
                int old = atomicCAS(&skey[h], -1, my);
                if (old == -1 || old == my) break;
            }
            h = (h + 1) & 4095;
        }
        atomicMin(&sval[h], s);
    }
    __syncthreads();
    // read-out phase
#pragma unroll
    for (int rep = 0; rep < 2; ++rep) {
        const int s = tid + rep * 1024;
        const int my = sidx[s];
        int h = (int)(((unsigned)my * 2654435761u) >> 16) & 4095;
        while (skey[h] != my) h = (h + 1) & 4095;
        const int mp = sval[h];
        first[s] = mp;
        if (mp == s) vocab_map[my] = s;
    }
}

// ---------------------------------------------------------------------------
// Kernel 2: fused q/k projection, 64x64 tile, BK=32, 512 threads (8 waves/CU
// = 2 waves/SIMD for latency hiding), 2x4 micro via ds_read_b64/b128
// (LDS stride 68 floats keeps rows 16B-aligned).
// cols 0..255 -> qbuf [T][256]; cols 256..511 -> kT [256][T] (transposed).
// ---------------------------------------------------------------------------
__global__ __launch_bounds__(512) void k_gemm_qk(const float* __restrict__ x,
                                                 const float* __restrict__ Wq,
                                                 const float* __restrict__ Wk,
                                                 float* __restrict__ qbuf,
                                                 float* __restrict__ kT) {
    __shared__ __align__(16) float As[32 * 68];   // [kk][row] transposed
    __shared__ __align__(16) float Bs[32 * 68];   // [kk][col]
    const int row0 = blockIdx.x * 64;
    const int col0 = blockIdx.y * 64;
    const bool is_q = (col0 < HQK);
    const float* __restrict__ W = is_q ? Wq : Wk;
    const int wc0 = is_q ? col0 : (col0 - HQK);
    const int tid = threadIdx.x;
    const int tr = (tid >> 4) << 1;     // 0..62 step 2
    const int tc = (tid & 15) << 2;     // 0..60 step 4
    const int ar = tid >> 3, ak = (tid & 7) << 2;    // A: 64 rows x 8 quads
    const int bk = tid >> 4, bc = (tid & 15) << 2;   // B: 32 k x 16 quads
    float acc[2][4] = {};
    for (int k0 = 0; k0 < C_DIM; k0 += 32) {
        float4 a4 = *reinterpret_cast<const float4*>(&x[(size_t)(row0 + ar) * C_DIM + k0 + ak]);
        float4 b4 = *reinterpret_cast<const float4*>(&W[(size_t)(k0 + bk) * HQK + wc0 + bc]);
        As[(ak + 0) * 68 + ar] = a4.x; As[(ak + 1) * 68 + ar] = a4.y;
        As[(ak + 2) * 68 + ar] = a4.z; As[(ak + 3) * 68 + ar] = a4.w;
        *reinterpret_cast<float4*>(&Bs[bk * 68 + bc]) = b4;
        __syncthreads();
#pragma unroll
        for (int kk = 0; kk < 32; ++kk) {
            float2 av = *reinterpret_cast<const float2*>(&As[kk * 68 + tr]);
            float4 bv = *reinterpret_cast<const float4*>(&Bs[kk * 68 + tc]);
            const float a[2] = {av.x, av.y};
            const float b[4] = {bv.x, bv.y, bv.z, bv.w};
#pragma unroll
            for (int i = 0; i < 2; ++i)
#pragma unroll
                for (int j = 0; j < 4; ++j) acc[i][j] = fmaf(a[i], b[j], acc[i][j]);
        }
        __syncthreads();
    }
    if (is_q) {
#pragma unroll
        for (int i = 0; i < 2; ++i) {
            float4 o = {acc[i][0], acc[i][1], acc[i][2], acc[i][3]};
            *reinterpret_cast<float4*>(&qbuf[(size_t)(row0 + tr + i) * HQK + col0 + tc]) = o;
        }
    } else {
#pragma unroll
        for (int j = 0; j < 4; ++j) {
            float2 o = {acc[0][j], acc[1][j]};
            *reinterpret_cast<float2*>(&kT[(size_t)(wc0 + tc + j) * T_CTX + row0 + tr]) = o;
        }
    }
}

// ---------------------------------------------------------------------------
// Kernel 3: causal score GEMM.  c[t][s] = q[t].k[s] / 256 for causal tiles
// (tile_s <= tile_t; diagonal garbage masked by the fold).  64x64 tile,
// BK=32, 512 threads, 2x4 micro; K=256 -> 8 iters.  Grid 32x32,
// upper-triangular blocks exit immediately.
// ---------------------------------------------------------------------------
__global__ __launch_bounds__(512) void k_scores_gemm(const float* __restrict__ q,
                                                     const float* __restrict__ kT,
                                                     float* __restrict__ c) {
    const int bt = blockIdx.x, bs = blockIdx.y;
    if (bs > bt) return;
    __shared__ __align__(16) float As[32 * 68];
    __shared__ __align__(16) float Bs[32 * 68];
    const int row0 = bt * 64;   // t
    const int col0 = bs * 64;   // s
    const int tid = threadIdx.x;
    const int tr = (tid >> 4) << 1;
    const int tc = (tid & 15) << 2;
    const int ar = tid >> 3, ak = (tid & 7) << 2;
    const int bk = tid >> 4, bc = (tid & 15) << 2;
    float acc[2][4] = {};
    for (int k0 = 0; k0 < HQK; k0 += 32) {
        float4 a4 = *reinterpret_cast<const float4*>(&q[(size_t)(row0 + ar) * HQK + k0 + ak]);
        float4 b4 = *reinterpret_cast<const float4*>(&kT[(size_t)(k0 + bk) * T_CTX + col0 + bc]);
        As[(ak + 0) * 68 + ar] = a4.x; As[(ak + 1) * 68 + ar] = a4.y;
        As[(ak + 2) * 68 + ar] = a4.z; As[(ak + 3) * 68 + ar] = a4.w;
        *reinterpret_cast<float4*>(&Bs[bk * 68 + bc]) = b4;
        __syncthreads();
#pragma unroll
        for (int kk = 0; kk < 32; ++kk) {
            float2 av = *reinterpret_cast<const float2*>(&As[kk * 68 + tr]);
            float4 bv = *reinterpret_cast<const float4*>(&Bs[kk * 68 + tc]);
            const float a[2] = {av.x, av.y};
            const float b[4] = {bv.x, bv.y, bv.z, bv.w};
#pragma unroll
            for (int i = 0; i < 2; ++i)
#pragma unroll
                for (int j = 0; j < 4; ++j) acc[i][j] = fmaf(a[i], b[j], acc[i][j]);
        }
        __syncthreads();
    }
    const float scale = 1.0f / 256.0f;
#pragma unroll
    for (int i = 0; i < 2; ++i) {
        float4 o = {acc[i][0] * scale, acc[i][1] * scale, acc[i][2] * scale, acc[i][3] * scale};
        *reinterpret_cast<float4*>(&c[(size_t)(row0 + tr + i) * T_CTX + col0 + tc]) = o;
    }
}

// ---------------------------------------------------------------------------
// Kernel 4 (fused fold+expand): block t
//   phase A: fold row t of c by first[] into LDS rowc[2048] (LDS atomics)
//   phase B: stream-expand rowc to out[t][0..VOCAB) with aligned nontemporal
//            float4 stores (per-row lead fixup since NVOC%4==1).
// out[t,v] = vocab_map[v] >= 0 ? rowc[vocab_map[v]] : 0
// ---------------------------------------------------------------------------
__global__ __launch_bounds__(256) void k_fold_expand(const float* __restrict__ c,
                                                     const int* __restrict__ first,
                                                     const int* __restrict__ vocab_map,
                                                     float* __restrict__ out) {
    __shared__ float rowc[T_CTX];
    const int t = blockIdx.x;
    for (int i = threadIdx.x; i < T_CTX; i += 256) rowc[i] = 0.0f;
    __syncthreads();
    // fold: s in [0, t]
    const int nq = (t >> 2) + 1;   // quads covering s=0..t
    for (int qd = threadIdx.x; qd < nq; qd += 256) {
        const int s0 = qd << 2;
        float4 v = *reinterpret_cast<const float4*>(&c[(size_t)t * T_CTX + s0]);
        int4 f4 = *reinterpret_cast<const int4*>(&first[s0]);
        if (s0 + 3 <= t) {
            atomicAdd(&rowc[f4.x], v.x); atomicAdd(&rowc[f4.y], v.y);
            atomicAdd(&rowc[f4.z], v.z); atomicAdd(&rowc[f4.w], v.w);
        } else {
            atomicAdd(&rowc[f4.x], v.x);
            if (s0 + 1 <= t) atomicAdd(&rowc[f4.y], v.y);
            if (s0 + 2 <= t) atomicAdd(&rowc[f4.z], v.z);
            if (s0 + 3 <= t) atomicAdd(&rowc[f4.w], v.w);
        }
    }
    __syncthreads();
    // expand
    float* __restrict__ orow = out + (size_t)t * NVOC;
    const int lead = (4 - (t & 3)) & 3;   // (t*NVOC + lead) % 4 == 0
    if ((int)threadIdx.x < lead) {
        int m = vocab_map[threadIdx.x];
        orow[threadIdx.x] = (m >= 0) ? rowc[m] : 0.0f;
    }
    const int nvec = (NVOC - lead) >> 2;
    for (int i = threadIdx.x; i < nvec; i += 256) {
        const int v = lead + (i << 2);
        int m0 = vocab_map[v + 0], m1 = vocab_map[v + 1];
        int m2 = vocab_map[v + 2], m3 = vocab_map[v + 3];
        nfloat4 o;
        o.x = (m0 >= 0) ? rowc[m0] : 0.0f;
        o.y = (m1 >= 0) ? rowc[m1] : 0.0f;
        o.z = (m2 >= 0) ? rowc[m2] : 0.0f;
        o.w = (m3 >= 0) ? rowc[m3] : 0.0f;
        __builtin_nontemporal_store(o, reinterpret_cast<nfloat4*>(&orow[v]));
    }
    for (int v = lead + (nvec << 2) + threadIdx.x; v < NVOC; v += 256) {
        int m = vocab_map[v];
        orow[v] = (m >= 0) ? rowc[m] : 0.0f;
    }
}

// ---------------------------------------------------------------------------
extern "C" void kernel_launch(void* const* d_in, const int* in_sizes, int n_in,
                              void* d_out, int out_size, void* d_ws, size_t ws_size,
                              hipStream_t stream) {
    const float* x   = (const float*)d_in[0];
    const int*   idx = (const int*)d_in[1];
    const float* Wq  = (const float*)d_in[2];
    const float* Wk  = (const float*)d_in[3];
    float* out = (float*)d_out;

    char* ws = (char*)d_ws;
    float* qbuf      = (float*)(ws);                              // 2 MB  [T][256]
    float* kT        = (float*)(ws + (2u << 20));                 // 2 MB  [256][T]
    float* c         = (float*)(ws + (4u << 20));                 // 16 MB [T][T] raw scores
    int*   first     = (int*)(ws + (20u << 20));                  // 8 KB
    int*   vocab_map = (int*)(ws + (20u << 20) + (16u << 10));    // ~200 KB

    k_build_first<<<1, 1024, 0, stream>>>(idx, first, vocab_map);
    dim3 gg(32, 8);
    k_gemm_qk<<<gg, 512, 0, stream>>>(x, Wq, Wk, qbuf, kT);
    dim3 gs(32, 32);
    k_scores_gemm<<<gs, 512, 0, stream>>>(qbuf, kT, c);
    k_fold_expand<<<T_CTX, 256, 0, stream>>>(c, first, vocab_map, out);
}